// Round 1
// baseline (614.025 us; speedup 1.0000x reference)
//
#include <hip/hip_runtime.h>
#include <stdint.h>

#define NN 100000
#define EE 1600000
#define DIM 64

__device__ __forceinline__ unsigned long long mix64(unsigned long long x){
  x += 0x9E3779B97F4A7C15ull;
  x = (x ^ (x >> 30)) * 0xBF58476D1CE4E5B9ull;
  x = (x ^ (x >> 27)) * 0x94D049BB133111EBull;
  return x ^ (x >> 31);
}

// h = x @ W^T + b   (x: [NN][64] f32, W: [64][64] row-major (out,in), b: [64])
extern "C" __global__ __launch_bounds__(256)
void k_linear(const float* __restrict__ x, const float* __restrict__ W,
              const float* __restrict__ b, float* __restrict__ h){
  __shared__ float wt[64][64];    // wt[i][o] = W[o][i]
  __shared__ float xs[128][68];   // +4 pad: conflict-free broadcast reads, 16B-aligned rows
  const int tid  = threadIdx.x;
  const int lane = tid & 63;
  const int w    = tid >> 6;

  // W^T into LDS (reads are tiny & L1/L2-hot; writes conflict-free)
  #pragma unroll
  for (int r = 0; r < 16; ++r){
    int i = r*4 + w;
    wt[i][lane] = W[lane*64 + i];
  }
  const int nbase = blockIdx.x * 128;
  #pragma unroll
  for (int r = 0; r < 8; ++r){
    int idx = r*256 + tid;       // float4 slot in [128][16]
    int nl  = idx >> 4;
    int c4  = idx & 15;
    int n   = nbase + nl;
    float4 v = make_float4(0.f,0.f,0.f,0.f);
    if (n < NN) v = reinterpret_cast<const float4*>(x)[(size_t)n*16 + c4];
    *reinterpret_cast<float4*>(&xs[nl][c4*4]) = v;
  }
  __syncthreads();

  const int og  = tid & 7;        // dim-octet
  const int nl0 = (tid >> 3) * 4; // 4 nodes per thread
  float acc[4][8];
  #pragma unroll
  for (int t=0;t<4;++t){
    #pragma unroll
    for (int j=0;j<8;++j) acc[t][j]=0.f;
  }
  #pragma unroll 4
  for (int i=0;i<64;++i){
    float4 wa = *reinterpret_cast<const float4*>(&wt[i][og*8]);
    float4 wb = *reinterpret_cast<const float4*>(&wt[i][og*8+4]);
    #pragma unroll
    for (int t=0;t<4;++t){
      float xv = xs[nl0+t][i];
      acc[t][0] += xv*wa.x; acc[t][1] += xv*wa.y;
      acc[t][2] += xv*wa.z; acc[t][3] += xv*wa.w;
      acc[t][4] += xv*wb.x; acc[t][5] += xv*wb.y;
      acc[t][6] += xv*wb.z; acc[t][7] += xv*wb.w;
    }
  }
  float4 b0 = reinterpret_cast<const float4*>(b)[og*2];
  float4 b1 = reinterpret_cast<const float4*>(b)[og*2+1];
  #pragma unroll
  for (int t=0;t<4;++t){
    int n = nbase + nl0 + t;
    if (n < NN){
      float4 o0 = make_float4(acc[t][0]+b0.x, acc[t][1]+b0.y, acc[t][2]+b0.z, acc[t][3]+b0.w);
      float4 o1 = make_float4(acc[t][4]+b1.x, acc[t][5]+b1.y, acc[t][6]+b1.z, acc[t][7]+b1.w);
      reinterpret_cast<float4*>(&h[(size_t)n*64])[og*2]   = o0;
      reinterpret_cast<float4*>(&h[(size_t)n*64])[og*2+1] = o1;
    }
  }
}

// Insert symmetrized edges + self loops into hash table (dedup).
extern "C" __global__ __launch_bounds__(256)
void k_insert(const int* __restrict__ ei, unsigned long long* __restrict__ table,
              unsigned int cmask){
  int e = blockIdx.x*256 + threadIdx.x;
  const int M = 2*EE + NN;
  if (e >= M) return;
  int s, d;
  if (e < EE)          { s = ei[e];            d = ei[EE + e]; }
  else if (e < 2*EE)   { int k = e - EE; s = ei[EE + k]; d = ei[k]; }
  else                 { s = e - 2*EE;         d = s; }
  unsigned long long key = (unsigned long long)s * (unsigned long long)NN
                         + (unsigned long long)d;
  unsigned int idx = (unsigned int)mix64(key) & cmask;
  const unsigned long long EMPTY = ~0ull;
  for (;;){
    unsigned long long prev = atomicCAS(&table[idx], EMPTY, key);
    if (prev == EMPTY || prev == key) break;
    idx = (idx + 1) & cmask;
  }
}

// Scan table; bucket unique edges by dst (fixed stride CAP), count in-degree.
extern "C" __global__ __launch_bounds__(256)
void k_place(const unsigned long long* __restrict__ table, int C,
             int* __restrict__ cnt, int* __restrict__ srclist, int CAP){
  int i = blockIdx.x*256 + threadIdx.x;
  if (i >= C) return;
  unsigned long long key = table[i];
  if (key == ~0ull) return;
  unsigned int s = (unsigned int)(key / NN);
  unsigned int d = (unsigned int)(key - (unsigned long long)s * NN);
  int pos = atomicAdd(&cnt[d], 1);
  if (pos < CAP) srclist[(size_t)d * CAP + pos] = (int)s;
}

extern "C" __global__ __launch_bounds__(256)
void k_inv(const int* __restrict__ cnt, float* __restrict__ inv){
  int n = blockIdx.x*256 + threadIdx.x;
  if (n < NN){
    int c = cnt[n]; if (c < 1) c = 1;
    inv[n] = 1.0f / sqrtf((float)c);
  }
}

// One wave per dst node; lane = output dim. out[d] = inv[d] * sum_s inv[s]*h[s]
extern "C" __global__ __launch_bounds__(256)
void k_agg(const float* __restrict__ h, const float* __restrict__ inv,
           const int* __restrict__ cnt, const int* __restrict__ srclist,
           float* __restrict__ out, int CAP){
  const int wv   = threadIdx.x >> 6;
  const int lane = threadIdx.x & 63;
  const int d    = blockIdx.x*4 + wv;
  if (d >= NN) return;
  int c = cnt[d]; if (c > CAP) c = CAP;
  const int* sl = srclist + (size_t)d * CAP;
  float acc = 0.f;
  for (int base = 0; base < c; base += 64){
    int m = c - base; if (m > 64) m = 64;
    int   sv = (lane < m) ? sl[base + lane] : 0;
    float iv = (lane < m) ? inv[sv] : 0.f;
    for (int j = 0; j < m; ++j){
      int   s = __shfl(sv, j);
      float w = __shfl(iv, j);
      acc += w * h[(size_t)s*64 + lane];
    }
  }
  out[(size_t)d*64 + lane] = acc * inv[d];
}

extern "C" void kernel_launch(void* const* d_in, const int* in_sizes, int n_in,
                              void* d_out, int out_size, void* d_ws, size_t ws_size,
                              hipStream_t stream){
  (void)in_sizes; (void)n_in;
  const float* x  = (const float*)d_in[0];
  const int*   ei = (const int*)  d_in[1];
  const float* W  = (const float*)d_in[2];
  const float* b  = (const float*)d_in[3];
  float* out = (float*)d_out;

  char* ws = (char*)d_ws;
  float* h   = (float*)ws;                    // 25,600,000 B
  int*   cnt = (int*)  (ws + 25600000);       //    400,000 B
  float* inv = (float*)(ws + 26000000);       //    400,000 B
  size_t off = 26400000;

  size_t rem = (ws_size > off) ? (ws_size - off) : 0;
  int Cbits = 23, CAP = 128;
  if (rem < (8ull << 23) + (size_t)NN*128*4){
    Cbits = 22; CAP = 96;
    if (rem < (8ull << 22) + (size_t)NN*96*4) CAP = 64;  // last resort
  }
  const size_t C = (size_t)1 << Cbits;
  unsigned long long* table = (unsigned long long*)(ws + off);
  int* srclist = (int*)(ws + off + 8*C);

  hipMemsetAsync(cnt,   0,    400000, stream);
  hipMemsetAsync(table, 0xFF, 8*C,    stream);

  k_linear<<<(NN + 127)/128, 256, 0, stream>>>(x, W, b, h);
  const int M = 2*EE + NN;
  k_insert<<<(M + 255)/256, 256, 0, stream>>>(ei, table, (unsigned int)(C - 1));
  k_place <<<(int)(C/256),  256, 0, stream>>>(table, (int)C, cnt, srclist, CAP);
  k_inv   <<<(NN + 255)/256,256, 0, stream>>>(cnt, inv);
  k_agg   <<<(NN + 3)/4,    256, 0, stream>>>(h, inv, cnt, srclist, out, CAP);
  (void)out_size;
}

// Round 2
// 393.585 us; speedup vs baseline: 1.5601x; 1.5601x over previous
//
#include <hip/hip_runtime.h>
#include <stdint.h>

#define NN 100000
#define EE 1600000
#define CAP 128           // hash slots per dst node (mean in-degree ~33)
#define EMPTY 0xFFFFFFFFu

__device__ __forceinline__ unsigned int mix32(unsigned int x){
  x ^= x >> 16; x *= 0x7feb352du;
  x ^= x >> 15; x *= 0x846ca68bu;
  x ^= x >> 16;
  return x;
}

// h = x @ W^T + b   (x: [NN][64] f32, W: [64][64] row-major (out,in), b: [64])
extern "C" __global__ __launch_bounds__(256)
void k_linear(const float* __restrict__ x, const float* __restrict__ W,
              const float* __restrict__ b, float* __restrict__ h){
  __shared__ float wt[64][64];    // wt[i][o] = W[o][i]
  __shared__ float xs[128][68];   // +4 pad
  const int tid  = threadIdx.x;
  const int lane = tid & 63;
  const int w    = tid >> 6;

  #pragma unroll
  for (int r = 0; r < 16; ++r){
    int i = r*4 + w;
    wt[i][lane] = W[lane*64 + i];
  }
  const int nbase = blockIdx.x * 128;
  #pragma unroll
  for (int r = 0; r < 8; ++r){
    int idx = r*256 + tid;
    int nl  = idx >> 4;
    int c4  = idx & 15;
    int n   = nbase + nl;
    float4 v = make_float4(0.f,0.f,0.f,0.f);
    if (n < NN) v = reinterpret_cast<const float4*>(x)[(size_t)n*16 + c4];
    *reinterpret_cast<float4*>(&xs[nl][c4*4]) = v;
  }
  __syncthreads();

  const int og  = tid & 7;
  const int nl0 = (tid >> 3) * 4;
  float acc[4][8];
  #pragma unroll
  for (int t=0;t<4;++t){
    #pragma unroll
    for (int j=0;j<8;++j) acc[t][j]=0.f;
  }
  #pragma unroll 4
  for (int i=0;i<64;++i){
    float4 wa = *reinterpret_cast<const float4*>(&wt[i][og*8]);
    float4 wb = *reinterpret_cast<const float4*>(&wt[i][og*8+4]);
    #pragma unroll
    for (int t=0;t<4;++t){
      float xv = xs[nl0+t][i];
      acc[t][0] += xv*wa.x; acc[t][1] += xv*wa.y;
      acc[t][2] += xv*wa.z; acc[t][3] += xv*wa.w;
      acc[t][4] += xv*wb.x; acc[t][5] += xv*wb.y;
      acc[t][6] += xv*wb.z; acc[t][7] += xv*wb.w;
    }
  }
  float4 b0 = reinterpret_cast<const float4*>(b)[og*2];
  float4 b1 = reinterpret_cast<const float4*>(b)[og*2+1];
  #pragma unroll
  for (int t=0;t<4;++t){
    int n = nbase + nl0 + t;
    if (n < NN){
      float4 o0 = make_float4(acc[t][0]+b0.x, acc[t][1]+b0.y, acc[t][2]+b0.z, acc[t][3]+b0.w);
      float4 o1 = make_float4(acc[t][4]+b1.x, acc[t][5]+b1.y, acc[t][6]+b1.z, acc[t][7]+b1.w);
      reinterpret_cast<float4*>(&h[(size_t)n*64])[og*2]   = o0;
      reinterpret_cast<float4*>(&h[(size_t)n*64])[og*2+1] = o1;
    }
  }
}

__device__ __forceinline__ void insert_edge(unsigned int* __restrict__ table,
                                            int s, int d){
  unsigned int* reg = table + (size_t)d * CAP;
  unsigned int idx = mix32((unsigned int)s) & (CAP-1);
  #pragma unroll 1
  for (int t = 0; t < CAP; ++t){
    unsigned int prev = atomicCAS(&reg[idx], EMPTY, (unsigned int)s);
    if (prev == EMPTY || prev == (unsigned int)s) return;
    idx = (idx + 1) & (CAP-1);
  }
}

// Symmetrize + self loops; dedup via per-dst open-addressed subtables.
extern "C" __global__ __launch_bounds__(256)
void k_insert(const int* __restrict__ ei, unsigned int* __restrict__ table){
  int e = blockIdx.x*256 + threadIdx.x;
  if (e < EE){
    int a = ei[e];
    int c = ei[EE + e];
    insert_edge(table, a, c);   // a -> c
    insert_edge(table, c, a);   // c -> a (symmetrize)
  } else if (e < EE + NN){
    int n = e - EE;
    insert_edge(table, n, n);   // self loop
  }
}

// One wave per dst: popcount valid slots -> inv[d] = 1/sqrt(deg)
extern "C" __global__ __launch_bounds__(256)
void k_count(const unsigned int* __restrict__ table, float* __restrict__ inv){
  const int wv   = threadIdx.x >> 6;
  const int lane = threadIdx.x & 63;
  const int d    = blockIdx.x*4 + wv;
  if (d >= NN) return;
  const unsigned int* reg = table + (size_t)d * CAP;
  unsigned int s0 = reg[lane];
  unsigned int s1 = reg[64 + lane];
  unsigned long long m0 = __ballot(s0 != EMPTY);
  unsigned long long m1 = __ballot(s1 != EMPTY);
  if (lane == 0){
    int c = __popcll(m0) + __popcll(m1);
    if (c < 1) c = 1;
    inv[d] = rsqrtf((float)c);
  }
}

// One wave per dst node; lane = output dim. out[d] = inv[d] * sum_s inv[s]*h[s]
extern "C" __global__ __launch_bounds__(256)
void k_agg(const float* __restrict__ h, const float* __restrict__ inv,
           const unsigned int* __restrict__ table, float* __restrict__ out){
  const int wv   = threadIdx.x >> 6;
  const int lane = threadIdx.x & 63;
  const int d    = blockIdx.x*4 + wv;
  if (d >= NN) return;
  const unsigned int* reg = table + (size_t)d * CAP;
  unsigned int s0 = reg[lane];
  unsigned int s1 = reg[64 + lane];
  float iv0 = (s0 != EMPTY) ? inv[s0] : 0.f;
  float iv1 = (s1 != EMPTY) ? inv[s1] : 0.f;
  unsigned long long m0 = __ballot(s0 != EMPTY);
  unsigned long long m1 = __ballot(s1 != EMPTY);

  float acc = 0.f;
  while (m0){
    int j = __builtin_ctzll(m0); m0 &= m0 - 1;
    int   s = __shfl((int)s0, j);
    float w = __shfl(iv0, j);
    acc += w * h[(size_t)s*64 + lane];
  }
  while (m1){
    int j = __builtin_ctzll(m1); m1 &= m1 - 1;
    int   s = __shfl((int)s1, j);
    float w = __shfl(iv1, j);
    acc += w * h[(size_t)s*64 + lane];
  }
  out[(size_t)d*64 + lane] = acc * inv[d];
}

extern "C" void kernel_launch(void* const* d_in, const int* in_sizes, int n_in,
                              void* d_out, int out_size, void* d_ws, size_t ws_size,
                              hipStream_t stream){
  (void)in_sizes; (void)n_in; (void)out_size; (void)ws_size;
  const float* x  = (const float*)d_in[0];
  const int*   ei = (const int*)  d_in[1];
  const float* W  = (const float*)d_in[2];
  const float* b  = (const float*)d_in[3];
  float* out = (float*)d_out;

  char* ws = (char*)d_ws;
  float*        h     = (float*)ws;                       // 25.6 MB
  float*        inv   = (float*)(ws + 25600000);          // 0.4 MB
  unsigned int* table = (unsigned int*)(ws + 26000000);   // NN*CAP*4 = 51.2 MB

  hipMemsetAsync(table, 0xFF, (size_t)NN * CAP * 4, stream);

  k_linear<<<(NN + 127)/128, 256, 0, stream>>>(x, W, b, h);
  const int M = EE + NN;
  k_insert<<<(M + 255)/256, 256, 0, stream>>>(ei, table);
  k_count <<<(NN + 3)/4,    256, 0, stream>>>(table, inv);
  k_agg   <<<(NN + 3)/4,    256, 0, stream>>>(h, inv, table, out);
}

// Round 3
// 311.325 us; speedup vs baseline: 1.9723x; 1.2642x over previous
//
#include <hip/hip_runtime.h>
#include <stdint.h>

#define NN 100000
#define EE 1600000
#define CAP 128           // hash slots per dst node (mean unique in-degree ~33, Poisson max < 80)
#define EMPTY 0xFFFFFFFFu

__device__ __forceinline__ unsigned int mix32(unsigned int x){
  x ^= x >> 16; x *= 0x7feb352du;
  x ^= x >> 15; x *= 0x846ca68bu;
  x ^= x >> 16;
  return x;
}

// h = x @ W^T + b   (x: [NN][64] f32, W: [64][64] row-major (out,in), b: [64])
extern "C" __global__ __launch_bounds__(256)
void k_linear(const float* __restrict__ x, const float* __restrict__ W,
              const float* __restrict__ b, float* __restrict__ h){
  __shared__ float wt[64][64];    // wt[i][o] = W[o][i]
  __shared__ float xs[128][68];   // +4 pad
  const int tid  = threadIdx.x;
  const int lane = tid & 63;
  const int w    = tid >> 6;

  #pragma unroll
  for (int r = 0; r < 16; ++r){
    int i = r*4 + w;
    wt[i][lane] = W[lane*64 + i];
  }
  const int nbase = blockIdx.x * 128;
  #pragma unroll
  for (int r = 0; r < 8; ++r){
    int idx = r*256 + tid;
    int nl  = idx >> 4;
    int c4  = idx & 15;
    int n   = nbase + nl;
    float4 v = make_float4(0.f,0.f,0.f,0.f);
    if (n < NN) v = reinterpret_cast<const float4*>(x)[(size_t)n*16 + c4];
    *reinterpret_cast<float4*>(&xs[nl][c4*4]) = v;
  }
  __syncthreads();

  const int og  = tid & 7;
  const int nl0 = (tid >> 3) * 4;
  float acc[4][8];
  #pragma unroll
  for (int t=0;t<4;++t){
    #pragma unroll
    for (int j=0;j<8;++j) acc[t][j]=0.f;
  }
  #pragma unroll 4
  for (int i=0;i<64;++i){
    float4 wa = *reinterpret_cast<const float4*>(&wt[i][og*8]);
    float4 wb = *reinterpret_cast<const float4*>(&wt[i][og*8+4]);
    #pragma unroll
    for (int t=0;t<4;++t){
      float xv = xs[nl0+t][i];
      acc[t][0] += xv*wa.x; acc[t][1] += xv*wa.y;
      acc[t][2] += xv*wa.z; acc[t][3] += xv*wa.w;
      acc[t][4] += xv*wb.x; acc[t][5] += xv*wb.y;
      acc[t][6] += xv*wb.z; acc[t][7] += xv*wb.w;
    }
  }
  float4 b0 = reinterpret_cast<const float4*>(b)[og*2];
  float4 b1 = reinterpret_cast<const float4*>(b)[og*2+1];
  #pragma unroll
  for (int t=0;t<4;++t){
    int n = nbase + nl0 + t;
    if (n < NN){
      float4 o0 = make_float4(acc[t][0]+b0.x, acc[t][1]+b0.y, acc[t][2]+b0.z, acc[t][3]+b0.w);
      float4 o1 = make_float4(acc[t][4]+b1.x, acc[t][5]+b1.y, acc[t][6]+b1.z, acc[t][7]+b1.w);
      reinterpret_cast<float4*>(&h[(size_t)n*64])[og*2]   = o0;
      reinterpret_cast<float4*>(&h[(size_t)n*64])[og*2+1] = o1;
    }
  }
}

__device__ __forceinline__ void insert_edge(unsigned int* __restrict__ table,
                                            int s, int d){
  unsigned int* reg = table + (size_t)d * CAP;
  unsigned int idx = mix32((unsigned int)s) & (CAP-1);
  #pragma unroll 1
  for (int t = 0; t < CAP; ++t){
    unsigned int prev = atomicCAS(&reg[idx], EMPTY, (unsigned int)s);
    if (prev == EMPTY || prev == (unsigned int)s) return;
    idx = (idx + 1) & (CAP-1);
  }
}

// One directed insert per thread: e < EE: ei0->ei1; e < 2EE: ei1->ei0; else self loop.
extern "C" __global__ __launch_bounds__(256)
void k_insert(const int* __restrict__ ei, unsigned int* __restrict__ table){
  int e = blockIdx.x*256 + threadIdx.x;
  if (e < 2*EE){
    int i = (e >= EE) ? (e - EE) : e;
    int a = ei[i];
    int c = ei[EE + i];
    int s = (e < EE) ? a : c;
    int d = (e < EE) ? c : a;
    insert_edge(table, s, d);
  } else if (e < 2*EE + NN){
    int n = e - 2*EE;
    insert_edge(table, n, n);
  }
}

// One wave per dst: compact valid slots to the region prefix (in-wave popcount
// compaction, no atomics), write cnt[d] and inv[d]=rsqrt(deg).
extern "C" __global__ __launch_bounds__(256)
void k_count(unsigned int* __restrict__ table, float* __restrict__ inv,
             int* __restrict__ cnt){
  const int wv   = threadIdx.x >> 6;
  const int lane = threadIdx.x & 63;
  const int d    = blockIdx.x*4 + wv;
  if (d >= NN) return;
  unsigned int* reg = table + (size_t)d * CAP;
  unsigned int s0 = reg[lane];
  unsigned int s1 = reg[64 + lane];
  bool v0 = (s0 != EMPTY), v1 = (s1 != EMPTY);
  unsigned long long m0 = __ballot(v0);
  unsigned long long m1 = __ballot(v1);
  int c0 = __popcll(m0);
  int c  = c0 + __popcll(m1);
  // All lanes' loads complete before any write (ballot forces it). v0 writes
  // land in [0,c0) within [0,64); v1 writes in [c0,c) — disjoint position sets.
  unsigned long long below = (1ull << lane) - 1ull;
  if (v0) reg[__popcll(m0 & below)]      = s0;
  if (v1) reg[c0 + __popcll(m1 & below)] = s1;
  if (lane == 0){
    cnt[d] = c;                  // c >= 1 (self loop always present)
    inv[d] = rsqrtf((float)c);
  }
}

// One wave per dst; lane = output dim. Counted loop over compacted src list,
// padded to a multiple of 8, with 8 independent accumulators (8 gathers in flight).
extern "C" __global__ __launch_bounds__(256)
void k_agg(const float* __restrict__ h, const float* __restrict__ inv,
           const int* __restrict__ cnt, const unsigned int* __restrict__ table,
           float* __restrict__ out){
  __shared__ unsigned int ss[4][CAP];
  __shared__ float        sw[4][CAP];
  const int wv   = threadIdx.x >> 6;
  const int lane = threadIdx.x & 63;
  const int d    = blockIdx.x*4 + wv;
  if (d >= NN) return;
  const unsigned int* reg = table + (size_t)d * CAP;
  const int c  = cnt[d];
  const int c8 = (c + 7) & ~7;

  if (lane < c){
    unsigned int s = reg[lane];
    ss[wv][lane] = s;
    sw[wv][lane] = inv[s];
  }
  if (64 + lane < c){
    unsigned int s = reg[64 + lane];
    ss[wv][64 + lane] = s;
    sw[wv][64 + lane] = inv[s];
  }
  {  // pad [c, c8) with zero-weight dummies (lane 0..7 covers)
    int p = c + lane;
    if (p < c8){ ss[wv][p] = 0; sw[wv][p] = 0.f; }
  }
  // Same wave wrote and reads this LDS — lockstep, no barrier needed.
  float acc[8];
  #pragma unroll
  for (int u = 0; u < 8; ++u) acc[u] = 0.f;
  #pragma unroll 1
  for (int j = 0; j < c8; j += 8){
    #pragma unroll
    for (int u = 0; u < 8; ++u){
      unsigned int s = ss[wv][j + u];
      float        w = sw[wv][j + u];
      acc[u] += w * h[(size_t)s * 64 + lane];
    }
  }
  float r = ((acc[0]+acc[1]) + (acc[2]+acc[3])) + ((acc[4]+acc[5]) + (acc[6]+acc[7]));
  out[(size_t)d*64 + lane] = r * inv[d];
}

extern "C" void kernel_launch(void* const* d_in, const int* in_sizes, int n_in,
                              void* d_out, int out_size, void* d_ws, size_t ws_size,
                              hipStream_t stream){
  (void)in_sizes; (void)n_in; (void)out_size; (void)ws_size;
  const float* x  = (const float*)d_in[0];
  const int*   ei = (const int*)  d_in[1];
  const float* W  = (const float*)d_in[2];
  const float* b  = (const float*)d_in[3];
  float* out = (float*)d_out;

  char* ws = (char*)d_ws;
  float*        h     = (float*)ws;                       // 25.6 MB
  float*        inv   = (float*)(ws + 25600000);          // 0.4 MB
  int*          cnt   = (int*)  (ws + 26000000);          // 0.4 MB
  unsigned int* table = (unsigned int*)(ws + 26400000);   // NN*CAP*4 = 51.2 MB

  hipMemsetAsync(table, 0xFF, (size_t)NN * CAP * 4, stream);

  k_linear<<<(NN + 127)/128, 256, 0, stream>>>(x, W, b, h);
  const int M = 2*EE + NN;
  k_insert<<<(M + 255)/256, 256, 0, stream>>>(ei, table);
  k_count <<<(NN + 3)/4,    256, 0, stream>>>(table, inv, cnt);
  k_agg   <<<(NN + 3)/4,    256, 0, stream>>>(h, inv, cnt, table, out);
}

// Round 4
// 218.063 us; speedup vs baseline: 2.8158x; 1.4277x over previous
//
#include <hip/hip_runtime.h>
#include <stdint.h>

#define NN 100000
#define EE 1600000
#define CAP 128           // srclist slots per dst (max unique in-degree ~70)
#define NB 782            // ceil(NN/128) dst buckets
#define CAPB 5120         // bucket capacity (mean 4220, sigma 65 -> 14 sigma headroom)
#define HTS 8192          // per-bucket LDS hash slots
#define EMPTY 0xFFFFFFFFu
#define BIN_CHUNK 4096    // input edge pairs per k_bin block

__device__ __forceinline__ unsigned int mix32(unsigned int x){
  x ^= x >> 16; x *= 0x7feb352du;
  x ^= x >> 15; x *= 0x846ca68bu;
  x ^= x >> 16;
  return x;
}

// h = x @ W^T + b   (x: [NN][64] f32, W: [64][64] row-major (out,in), b: [64])
extern "C" __global__ __launch_bounds__(256)
void k_linear(const float* __restrict__ x, const float* __restrict__ W,
              const float* __restrict__ b, float* __restrict__ h){
  __shared__ float wt[64][64];    // wt[i][o] = W[o][i]
  __shared__ float xs[128][68];   // +4 pad
  const int tid  = threadIdx.x;
  const int lane = tid & 63;
  const int w    = tid >> 6;

  #pragma unroll
  for (int r = 0; r < 16; ++r){
    int i = r*4 + w;
    wt[i][lane] = W[lane*64 + i];
  }
  const int nbase = blockIdx.x * 128;
  #pragma unroll
  for (int r = 0; r < 8; ++r){
    int idx = r*256 + tid;
    int nl  = idx >> 4;
    int c4  = idx & 15;
    int n   = nbase + nl;
    float4 v = make_float4(0.f,0.f,0.f,0.f);
    if (n < NN) v = reinterpret_cast<const float4*>(x)[(size_t)n*16 + c4];
    *reinterpret_cast<float4*>(&xs[nl][c4*4]) = v;
  }
  __syncthreads();

  const int og  = tid & 7;
  const int nl0 = (tid >> 3) * 4;
  float acc[4][8];
  #pragma unroll
  for (int t=0;t<4;++t){
    #pragma unroll
    for (int j=0;j<8;++j) acc[t][j]=0.f;
  }
  #pragma unroll 4
  for (int i=0;i<64;++i){
    float4 wa = *reinterpret_cast<const float4*>(&wt[i][og*8]);
    float4 wb = *reinterpret_cast<const float4*>(&wt[i][og*8+4]);
    #pragma unroll
    for (int t=0;t<4;++t){
      float xv = xs[nl0+t][i];
      acc[t][0] += xv*wa.x; acc[t][1] += xv*wa.y;
      acc[t][2] += xv*wa.z; acc[t][3] += xv*wa.w;
      acc[t][4] += xv*wb.x; acc[t][5] += xv*wb.y;
      acc[t][6] += xv*wb.z; acc[t][7] += xv*wb.w;
    }
  }
  float4 b0 = reinterpret_cast<const float4*>(b)[og*2];
  float4 b1 = reinterpret_cast<const float4*>(b)[og*2+1];
  #pragma unroll
  for (int t=0;t<4;++t){
    int n = nbase + nl0 + t;
    if (n < NN){
      float4 o0 = make_float4(acc[t][0]+b0.x, acc[t][1]+b0.y, acc[t][2]+b0.z, acc[t][3]+b0.w);
      float4 o1 = make_float4(acc[t][4]+b1.x, acc[t][5]+b1.y, acc[t][6]+b1.z, acc[t][7]+b1.w);
      reinterpret_cast<float4*>(&h[(size_t)n*64])[og*2]   = o0;
      reinterpret_cast<float4*>(&h[(size_t)n*64])[og*2+1] = o1;
    }
  }
}

// Partition directed edges (both directions) into dst buckets of 128 nodes.
// Packed entry: src<<7 | (dst&127). Bucket id = dst>>7.
extern "C" __global__ __launch_bounds__(256)
void k_bin(const int* __restrict__ ei, int* __restrict__ bcnt,
           unsigned int* __restrict__ bbuf){
  __shared__ int hist[NB];
  __shared__ int bbase[NB];
  __shared__ int bcur[NB];
  const int tid = threadIdx.x;
  for (int i = tid; i < NB; i += 256) hist[i] = 0;
  __syncthreads();
  const int e0 = blockIdx.x * BIN_CHUNK;
  #pragma unroll 1
  for (int r = 0; r < BIN_CHUNK; r += 256){
    int i = e0 + r + tid;
    if (i < EE){
      int a = ei[i], c = ei[EE + i];
      atomicAdd(&hist[c >> 7], 1);   // edge a->c lands in dst-bucket of c
      atomicAdd(&hist[a >> 7], 1);   // edge c->a lands in dst-bucket of a
    }
  }
  __syncthreads();
  for (int bk = tid; bk < NB; bk += 256){
    int hh = hist[bk];
    bbase[bk] = hh ? atomicAdd(&bcnt[bk], hh) : 0;
    bcur[bk]  = 0;
  }
  __syncthreads();
  #pragma unroll 1
  for (int r = 0; r < BIN_CHUNK; r += 256){
    int i = e0 + r + tid;
    if (i < EE){
      int a = ei[i], c = ei[EE + i];
      int b1 = c >> 7, b2 = a >> 7;
      int p1 = bbase[b1] + atomicAdd(&bcur[b1], 1);
      int p2 = bbase[b2] + atomicAdd(&bcur[b2], 1);
      if (p1 < CAPB) bbuf[(size_t)b1*CAPB + p1] = ((unsigned)a << 7) | (unsigned)(c & 127);
      if (p2 < CAPB) bbuf[(size_t)b2*CAPB + p2] = ((unsigned)c << 7) | (unsigned)(a & 127);
    }
  }
}

// One block per bucket: dedup in LDS hash, inject self loops, emit
// cnt/inv and compacted per-dst src lists.
extern "C" __global__ __launch_bounds__(256)
void k_dedup(const int* __restrict__ bcnt, const unsigned int* __restrict__ bbuf,
             unsigned int* __restrict__ srclist, int* __restrict__ cnt,
             float* __restrict__ inv){
  __shared__ unsigned int HT[HTS];   // 32KB
  __shared__ int dcnt[128], dcur[128];
  const int tid = threadIdx.x;
  const int b   = blockIdx.x;
  const int d0  = b << 7;
  for (int i = tid; i < HTS; i += 256) HT[i] = EMPTY;
  if (tid < 128){ dcnt[tid] = 0; dcur[tid] = 0; }
  __syncthreads();

  int n = bcnt[b]; if (n > CAPB) n = CAPB;
  const unsigned int* buf = bbuf + (size_t)b * CAPB;
  for (int k = tid; k < n; k += 256){
    unsigned int pk  = buf[k];
    unsigned int idx = mix32(pk) & (HTS-1);
    for (;;){
      unsigned int prev = atomicCAS(&HT[idx], EMPTY, pk);
      if (prev == EMPTY || prev == pk) break;
      idx = (idx + 1) & (HTS-1);
    }
  }
  if (tid < 128 && d0 + tid < NN){      // self loop (src=dst=d0+tid)
    unsigned int pk  = ((unsigned)(d0 + tid) << 7) | (unsigned)tid;
    unsigned int idx = mix32(pk) & (HTS-1);
    for (;;){
      unsigned int prev = atomicCAS(&HT[idx], EMPTY, pk);
      if (prev == EMPTY || prev == pk) break;
      idx = (idx + 1) & (HTS-1);
    }
  }
  __syncthreads();

  for (int i = tid; i < HTS; i += 256){
    unsigned int v = HT[i];
    if (v != EMPTY) atomicAdd(&dcnt[v & 127], 1);
  }
  __syncthreads();
  if (tid < 128 && d0 + tid < NN){
    int c = dcnt[tid];
    cnt[d0 + tid] = c;
    inv[d0 + tid] = rsqrtf((float)c);
  }
  __syncthreads();
  for (int i = tid; i < HTS; i += 256){
    unsigned int v = HT[i];
    if (v != EMPTY){
      int dl  = v & 127;
      int pos = atomicAdd(&dcur[dl], 1);
      if (pos < CAP) srclist[(size_t)(d0 + dl) * CAP + pos] = v >> 7;
    }
  }
}

// One wave per dst; lane = output dim. Counted loop over compacted src list,
// 8 independent accumulators (8 gathers in flight).
extern "C" __global__ __launch_bounds__(256)
void k_agg(const float* __restrict__ h, const float* __restrict__ inv,
           const int* __restrict__ cnt, const unsigned int* __restrict__ srclist,
           float* __restrict__ out){
  __shared__ unsigned int ss[4][CAP];
  __shared__ float        sw[4][CAP];
  const int wv   = threadIdx.x >> 6;
  const int lane = threadIdx.x & 63;
  const int d    = blockIdx.x*4 + wv;
  if (d >= NN) return;
  const unsigned int* reg = srclist + (size_t)d * CAP;
  int c = cnt[d]; if (c > CAP) c = CAP;
  const int c8 = (c + 7) & ~7;

  if (lane < c){
    unsigned int s = reg[lane];
    ss[wv][lane] = s;
    sw[wv][lane] = inv[s];
  }
  if (64 + lane < c){
    unsigned int s = reg[64 + lane];
    ss[wv][64 + lane] = s;
    sw[wv][64 + lane] = inv[s];
  }
  {  // pad [c, c8) with zero-weight dummies
    int p = c + lane;
    if (p < c8){ ss[wv][p] = 0; sw[wv][p] = 0.f; }
  }
  float acc[8];
  #pragma unroll
  for (int u = 0; u < 8; ++u) acc[u] = 0.f;
  #pragma unroll 1
  for (int j = 0; j < c8; j += 8){
    #pragma unroll
    for (int u = 0; u < 8; ++u){
      unsigned int s = ss[wv][j + u];
      float        w = sw[wv][j + u];
      acc[u] += w * h[(size_t)s * 64 + lane];
    }
  }
  float r = ((acc[0]+acc[1]) + (acc[2]+acc[3])) + ((acc[4]+acc[5]) + (acc[6]+acc[7]));
  out[(size_t)d*64 + lane] = r * inv[d];
}

extern "C" void kernel_launch(void* const* d_in, const int* in_sizes, int n_in,
                              void* d_out, int out_size, void* d_ws, size_t ws_size,
                              hipStream_t stream){
  (void)in_sizes; (void)n_in; (void)out_size; (void)ws_size;
  const float* x  = (const float*)d_in[0];
  const int*   ei = (const int*)  d_in[1];
  const float* W  = (const float*)d_in[2];
  const float* b  = (const float*)d_in[3];
  float* out = (float*)d_out;

  char* ws = (char*)d_ws;
  float*        h       = (float*)ws;                       // 25.6 MB
  float*        inv     = (float*)(ws + 25600000);          // 0.4 MB
  int*          cnt     = (int*)  (ws + 26000000);          // 0.4 MB
  unsigned int* srclist = (unsigned int*)(ws + 26400000);   // 51.2 MB
  int*          bcnt    = (int*)  (ws + 77600000);          // 3.1 KB
  unsigned int* bbuf    = (unsigned int*)(ws + 77604096);   // 16.0 MB (end ~93.6 MB)

  hipMemsetAsync(bcnt, 0, NB * 4, stream);

  k_linear<<<(NN + 127)/128, 256, 0, stream>>>(x, W, b, h);
  k_bin   <<<(EE + BIN_CHUNK - 1)/BIN_CHUNK, 256, 0, stream>>>(ei, bcnt, bbuf);
  k_dedup <<<NB, 256, 0, stream>>>(bcnt, bbuf, srclist, cnt, inv);
  k_agg   <<<(NN + 3)/4, 256, 0, stream>>>(h, inv, cnt, srclist, out);
}

// Round 5
// 155.810 us; speedup vs baseline: 3.9409x; 1.3995x over previous
//
#include <hip/hip_runtime.h>
#include <hip/hip_bf16.h>
#include <stdint.h>

#define NN 100000
#define EE 1600000
#define CAP 128           // srclist slots per dst (max unique in-degree ~70)
#define NB 782            // ceil(NN/128) dst buckets
#define CAPB 5120         // bucket capacity (mean 4220, sigma ~65)
#define HTS 8192          // per-bucket LDS hash slots
#define EMPTY 0xFFFFFFFFu
#define BIN_CHUNK 4096    // input edge pairs per bin block
#define GL 782            // linear blocks: ceil(NN/128)
#define GB ((EE + BIN_CHUNK - 1) / BIN_CHUNK)   // 391 bin blocks

__device__ __forceinline__ unsigned int mix32(unsigned int x){
  x ^= x >> 16; x *= 0x7feb352du;
  x ^= x >> 15; x *= 0x846ca68bu;
  x ^= x >> 16;
  return x;
}

// Fused: blocks [0,GL) compute h = bf16(x @ W^T + b); blocks [GL,GL+GB) bin edges.
extern "C" __global__ __launch_bounds__(256)
void k_prep(const float* __restrict__ x, const float* __restrict__ W,
            const float* __restrict__ bias, __hip_bfloat16* __restrict__ hb,
            const int* __restrict__ ei, int* __restrict__ bcnt,
            unsigned int* __restrict__ bbuf){
  __shared__ __align__(16) char sm[51200];
  const int tid = threadIdx.x;

  if (blockIdx.x < GL){
    // ---------------- linear path ----------------
    float (*wt)[64] = reinterpret_cast<float(*)[64]>(sm);            // 16 KB
    float (*xs)[68] = reinterpret_cast<float(*)[68]>(sm + 16384);    // 34.8 KB
    const int lane = tid & 63;
    const int w    = tid >> 6;
    #pragma unroll
    for (int r = 0; r < 16; ++r){
      int i = r*4 + w;
      wt[i][lane] = W[lane*64 + i];
    }
    const int nbase = blockIdx.x * 128;
    #pragma unroll
    for (int r = 0; r < 8; ++r){
      int idx = r*256 + tid;
      int nl  = idx >> 4;
      int c4  = idx & 15;
      int n   = nbase + nl;
      float4 v = make_float4(0.f,0.f,0.f,0.f);
      if (n < NN) v = reinterpret_cast<const float4*>(x)[(size_t)n*16 + c4];
      *reinterpret_cast<float4*>(&xs[nl][c4*4]) = v;
    }
    __syncthreads();

    const int og  = tid & 7;
    const int nl0 = (tid >> 3) * 4;
    float acc[4][8];
    #pragma unroll
    for (int t=0;t<4;++t){
      #pragma unroll
      for (int j=0;j<8;++j) acc[t][j]=0.f;
    }
    #pragma unroll 4
    for (int i=0;i<64;++i){
      float4 wa = *reinterpret_cast<const float4*>(&wt[i][og*8]);
      float4 wb = *reinterpret_cast<const float4*>(&wt[i][og*8+4]);
      #pragma unroll
      for (int t=0;t<4;++t){
        float xv = xs[nl0+t][i];
        acc[t][0] += xv*wa.x; acc[t][1] += xv*wa.y;
        acc[t][2] += xv*wa.z; acc[t][3] += xv*wa.w;
        acc[t][4] += xv*wb.x; acc[t][5] += xv*wb.y;
        acc[t][6] += xv*wb.z; acc[t][7] += xv*wb.w;
      }
    }
    float4 b0 = reinterpret_cast<const float4*>(bias)[og*2];
    float4 b1 = reinterpret_cast<const float4*>(bias)[og*2+1];
    float bb[8] = {b0.x,b0.y,b0.z,b0.w,b1.x,b1.y,b1.z,b1.w};
    #pragma unroll
    for (int t=0;t<4;++t){
      int n = nbase + nl0 + t;
      if (n < NN){
        union { uint4 u4; __hip_bfloat16 v[8]; } pk;
        #pragma unroll
        for (int j=0;j<8;++j) pk.v[j] = __float2bfloat16(acc[t][j] + bb[j]);
        reinterpret_cast<uint4*>(&hb[(size_t)n*64])[og] = pk.u4;
      }
    }
  } else {
    // ---------------- bin path ----------------
    int* hist  = reinterpret_cast<int*>(sm);
    int* bbase = hist + NB;
    int* bcur  = bbase + NB;
    for (int i = tid; i < NB; i += 256) hist[i] = 0;
    __syncthreads();
    const int e0 = (blockIdx.x - GL) * BIN_CHUNK;
    #pragma unroll 1
    for (int r = 0; r < BIN_CHUNK; r += 256){
      int i = e0 + r + tid;
      if (i < EE){
        int a = ei[i], c = ei[EE + i];
        atomicAdd(&hist[c >> 7], 1);
        atomicAdd(&hist[a >> 7], 1);
      }
    }
    __syncthreads();
    for (int bk = tid; bk < NB; bk += 256){
      int hh = hist[bk];
      bbase[bk] = hh ? atomicAdd(&bcnt[bk], hh) : 0;
      bcur[bk]  = 0;
    }
    __syncthreads();
    #pragma unroll 1
    for (int r = 0; r < BIN_CHUNK; r += 256){
      int i = e0 + r + tid;
      if (i < EE){
        int a = ei[i], c = ei[EE + i];
        int b1 = c >> 7, b2 = a >> 7;
        int p1 = bbase[b1] + atomicAdd(&bcur[b1], 1);
        int p2 = bbase[b2] + atomicAdd(&bcur[b2], 1);
        if (p1 < CAPB) bbuf[(size_t)b1*CAPB + p1] = ((unsigned)a << 7) | (unsigned)(c & 127);
        if (p2 < CAPB) bbuf[(size_t)b2*CAPB + p2] = ((unsigned)c << 7) | (unsigned)(a & 127);
      }
    }
  }
}

// One block per bucket: dedup in LDS hash, inject self loops, emit
// cnt/inv and compacted per-dst src lists.
extern "C" __global__ __launch_bounds__(256)
void k_dedup(const int* __restrict__ bcnt, const unsigned int* __restrict__ bbuf,
             unsigned int* __restrict__ srclist, int* __restrict__ cnt,
             float* __restrict__ inv){
  __shared__ unsigned int HT[HTS];   // 32KB
  __shared__ int dcnt[128], dcur[128];
  const int tid = threadIdx.x;
  const int b   = blockIdx.x;
  const int d0  = b << 7;
  for (int i = tid; i < HTS; i += 256) HT[i] = EMPTY;
  if (tid < 128){ dcnt[tid] = 0; dcur[tid] = 0; }
  __syncthreads();

  int n = bcnt[b]; if (n > CAPB) n = CAPB;
  const unsigned int* buf = bbuf + (size_t)b * CAPB;
  for (int k = tid; k < n; k += 256){
    unsigned int pk  = buf[k];
    unsigned int idx = mix32(pk) & (HTS-1);
    for (;;){
      unsigned int prev = atomicCAS(&HT[idx], EMPTY, pk);
      if (prev == EMPTY || prev == pk) break;
      idx = (idx + 1) & (HTS-1);
    }
  }
  if (tid < 128 && d0 + tid < NN){      // self loop (src=dst=d0+tid)
    unsigned int pk  = ((unsigned)(d0 + tid) << 7) | (unsigned)tid;
    unsigned int idx = mix32(pk) & (HTS-1);
    for (;;){
      unsigned int prev = atomicCAS(&HT[idx], EMPTY, pk);
      if (prev == EMPTY || prev == pk) break;
      idx = (idx + 1) & (HTS-1);
    }
  }
  __syncthreads();

  for (int i = tid; i < HTS; i += 256){
    unsigned int v = HT[i];
    if (v != EMPTY) atomicAdd(&dcnt[v & 127], 1);
  }
  __syncthreads();
  if (tid < 128 && d0 + tid < NN){
    int c = dcnt[tid];
    cnt[d0 + tid] = c;
    inv[d0 + tid] = rsqrtf((float)c);
  }
  __syncthreads();
  for (int i = tid; i < HTS; i += 256){
    unsigned int v = HT[i];
    if (v != EMPTY){
      int dl  = v & 127;
      int pos = atomicAdd(&dcur[dl], 1);
      if (pos < CAP) srclist[(size_t)(d0 + dl) * CAP + pos] = v >> 7;
    }
  }
}

// One wave per dst; lane = output dim. Counted loop over compacted src list,
// 8 independent bf16 row-gathers in flight per wave.
extern "C" __global__ __launch_bounds__(256)
void k_agg(const __hip_bfloat16* __restrict__ hb, const float* __restrict__ inv,
           const int* __restrict__ cnt, const unsigned int* __restrict__ srclist,
           float* __restrict__ out){
  __shared__ unsigned int ss[4][CAP];
  __shared__ float        sw[4][CAP];
  const int wv   = threadIdx.x >> 6;
  const int lane = threadIdx.x & 63;
  const int d    = blockIdx.x*4 + wv;
  if (d >= NN) return;
  const unsigned int* reg = srclist + (size_t)d * CAP;
  int c = cnt[d]; if (c > CAP) c = CAP;
  const int c8 = (c + 7) & ~7;

  if (lane < c){
    unsigned int s = reg[lane];
    ss[wv][lane] = s;
    sw[wv][lane] = inv[s];
  }
  if (64 + lane < c){
    unsigned int s = reg[64 + lane];
    ss[wv][64 + lane] = s;
    sw[wv][64 + lane] = inv[s];
  }
  {  // pad [c, c8) with zero-weight dummies
    int p = c + lane;
    if (p < c8){ ss[wv][p] = 0; sw[wv][p] = 0.f; }
  }
  float acc[8];
  #pragma unroll
  for (int u = 0; u < 8; ++u) acc[u] = 0.f;
  #pragma unroll 1
  for (int j = 0; j < c8; j += 8){
    #pragma unroll
    for (int u = 0; u < 8; ++u){
      unsigned int s = ss[wv][j + u];
      float        w = sw[wv][j + u];
      float       hv = __bfloat162float(hb[(size_t)s * 64 + lane]);
      acc[u] += w * hv;
    }
  }
  float r = ((acc[0]+acc[1]) + (acc[2]+acc[3])) + ((acc[4]+acc[5]) + (acc[6]+acc[7]));
  out[(size_t)d*64 + lane] = r * inv[d];
}

extern "C" void kernel_launch(void* const* d_in, const int* in_sizes, int n_in,
                              void* d_out, int out_size, void* d_ws, size_t ws_size,
                              hipStream_t stream){
  (void)in_sizes; (void)n_in; (void)out_size; (void)ws_size;
  const float* x  = (const float*)d_in[0];
  const int*   ei = (const int*)  d_in[1];
  const float* W  = (const float*)d_in[2];
  const float* b  = (const float*)d_in[3];
  float* out = (float*)d_out;

  char* ws = (char*)d_ws;
  __hip_bfloat16* hb      = (__hip_bfloat16*)ws;            // 12.8 MB
  float*          inv     = (float*)(ws + 12800000);        // 0.4 MB
  int*            cnt     = (int*)  (ws + 13200000);        // 0.4 MB
  unsigned int*   srclist = (unsigned int*)(ws + 13600000); // 51.2 MB
  int*            bcnt    = (int*)  (ws + 64800000);        // 4 KB
  unsigned int*   bbuf    = (unsigned int*)(ws + 64804096); // 16.0 MB (end ~80.8 MB)

  hipMemsetAsync(bcnt, 0, NB * 4, stream);

  k_prep  <<<GL + GB, 256, 0, stream>>>(x, W, b, hb, ei, bcnt, bbuf);
  k_dedup <<<NB, 256, 0, stream>>>(bcnt, bbuf, srclist, cnt, inv);
  k_agg   <<<(NN + 3)/4, 256, 0, stream>>>(hb, inv, cnt, srclist, out);
}